// Round 9
// baseline (234.245 us; speedup 1.0000x reference)
//
#include <hip/hip_runtime.h>
#include <stdint.h>

// Problem constants (match reference)
#define NP 32    // num networks (P)
#define NH 128   // hidden (H)
#define NB 32    // batch (B)
#define NT 256   // time (T)
#define FH 512   // 4*H

typedef __attribute__((ext_vector_type(4))) float float4_t;
typedef __attribute__((ext_vector_type(8))) __bf16 bf16x8;
typedef __attribute__((ext_vector_type(4))) __bf16 bf16x4;

static __device__ __forceinline__ float4_t mfma_bf16(bf16x8 a, bf16x8 b, float4_t c) {
  return __builtin_amdgcn_mfma_f32_16x16x32_bf16(a, b, c, 0, 0, 0);
}

#define LOG2E 1.4426950408889634f

// Raw workgroup barrier: drains LDS ops only (cross-wave h visibility), does
// NOT drain vmcnt — pending global loads/stores stay in flight across it.
#define BAR() __asm__ volatile("s_waitcnt lgkmcnt(0)\n\ts_barrier" ::: "memory")
#define SB()  __builtin_amdgcn_sched_barrier(0)

// ---------------------------------------------------------------------------
// R17: WAVE-STAGGERED gate streaming. R16 post-mortem: segmenting act between
// MFMA groups stalls the wave at the act's data dep and (in-order issue)
// blocks the LATER MFMAs behind it — both SIMD-mates stall simultaneously
// (identical code) -> pipe drains -> neutral/worse. R15's all-MFMA-first is
// optimal for a SHARED order. Fix: SIMD-mates get STAGGERED gate orders
// (waves 0-3: g0,g1,g2,g3; waves 4-7: g2,g3,g0,g1; mates = {w, w+4} under
// w%4 SIMD round-robin). When the even wave stalls on act-i (g0 chain done
// ~pipe-pos 200), the odd wave's g2 MFMAs feed the pipe, and vice versa.
// SB() pins [chain][act] pair boundaries (R16: SB alone ~free; stagger is
// the missing piece). Budget: pipe 40 MFMA/SIMD = 776 cyc; acts (~180/wave)
// sit in mate-stall windows; step -> 776 + c-tail + write + BAR ~ 1000-1130
// vs R15's 1533.
// Also: XCD-aware net map (net = bid&31): all 8 blocks of a net hit ONE
// XCD L2 -> weight FETCH 42->~15MB, faster weight-load prologue.
// SESSION RULES: launch_bounds 2nd arg never !=1 (R9-R11 spill death);
// waves_per_eu(2,2) is the trusted 256-reg knob (R15); no DS ops in loop
// beyond h write/read (R5); co-residency null at issue saturation (R14);
// M=4/256 blocks is the dup-optimal CU partition (R12/R15; M=2 dual-stream
// floor 1590 > 1533 — overlap via more blocks/CU is arithmetically dead).
// ---------------------------------------------------------------------------

// Prepass: X f32 -> bf16 into ws (same [B][T][P] layout). 262144 elems.
__global__ __launch_bounds__(512, 1) void xcvt(
    const float* __restrict__ X, __bf16* __restrict__ Xb)
{
  const int i = (blockIdx.x * 512 + threadIdx.x) * 4;
  float4_t v = *(const float4_t*)(X + i);
  bf16x4 o;
#pragma unroll
  for (int j = 0; j < 4; ++j) o[j] = (__bf16)v[j];
  *(bf16x4*)(Xb + i) = o;
}

__global__ __attribute__((amdgpu_flat_work_group_size(512, 512),
                          amdgpu_waves_per_eu(2, 2)))
void clstm_fused5(
    const __bf16* __restrict__ Xb, const float* __restrict__ Wih,
    const float* __restrict__ Whh, const float* __restrict__ bih,
    const float* __restrict__ bhh, const float* __restrict__ Wout,
    const float* __restrict__ bout, float* __restrict__ out)
{
  // XCD swizzle: blocks {n, n+32, ..., n+224} share net n and all have
  // bid%8 == n%8 -> same XCD -> weights live in ONE XCD's L2.
  const int net = blockIdx.x & 31, bq = blockIdx.x >> 5;
  const int tid = threadIdx.x;
  const int w = tid >> 6, lane = tid & 63;
  const int quad = lane >> 4, l16 = lane & 15;

  // h A-fragments, double buffered, 4 DISTINCT rows: [buf][kc][kquad][m<4][j]
  __shared__ __bf16 hfrag[2][4][4][4][8];   // 2 KB total

  { ((int*)hfrag)[tid] = 0; }   // h0 = 0, both buffers
  __syncthreads();

  // ---- load weights into register B-fragments (one-time) ----
  // B-frag layout for 16x16x32: lane holds B[k = quad*8 + j][n = l16].
  bf16x8 bfrag[4][5];
  float4_t bias4[4];
#pragma unroll
  for (int g = 0; g < 4; ++g) {
    const float scale = (g == 2) ? (-2.0f*LOG2E) : (-LOG2E);
    const int col = g*NH + w*16 + l16;
#pragma unroll
    for (int kc = 0; kc < 5; ++kc) {
      const float* src = (kc == 0) ? (Wih + ((size_t)net*FH + col)*NP + quad*8)
                                   : (Whh + ((size_t)net*FH + col)*NH + (kc-1)*32 + quad*8);
      bf16x8 bf;
#pragma unroll
      for (int j = 0; j < 8; ++j) bf[j] = (__bf16)(src[j] * scale);
      bfrag[g][kc] = bf;
    }
    const float b = (bih[net*FH + col] + bhh[net*FH + col]) * scale;
    bias4[g] = (float4_t){b, b, b, b};
  }

  // head B-frags (all waves — head rotates): B[k][n] = wout[k] broadcast.
  bf16x8 wof[4];
#pragma unroll
  for (int kc = 0; kc < 4; ++kc) {
    const float* wp = Wout + net*NH + kc*32 + quad*8;
#pragma unroll
    for (int j = 0; j < 8; ++j) wof[kc][j] = (__bf16)wp[j];
  }
  const float bo = bout[net];

  // c state, PRE-SCALED by -2log2e (saves a mul on the h critical chain)
  float cs = 0.f;
  const float S2 = -2.0f*LOG2E;

  // x source (bf16 prepass, layout == X): batch bq*4 + (l16&3) (4x dup)
  int xoff = (bq*4 + (l16 & 3))*(NT*NP) + quad*8;

  // h write coords for unit u = w*16 + l16; row = quad (this lane's batch)
  const int kcp = w >> 1, q2 = ((w & 1) << 1) | (l16 >> 3), jj = l16 & 7;

  // head store base: out[(bq*4 + r)*NT*NP + t*NP + net]
  float* outp = out + ((size_t)bq*4)*(NT*NP) + net;

  // preload ax for t=0
  bf16x8 ax = *(const bf16x8*)(Xb + xoff);
  xoff += NP;

// ---- 5-deep serial MFMA chain for gate G (bias as C-init, R15-proven) ----
#define CHAIN(G)                                                              \
    a##G = mfma_bf16(ax,  bfrag[G][0], bias4[G]);                             \
    a##G = mfma_bf16(ah0, bfrag[G][1], a##G);                                 \
    a##G = mfma_bf16(ah1, bfrag[G][2], a##G);                                 \
    a##G = mfma_bf16(ah2, bfrag[G][3], a##G);                                 \
    a##G = mfma_bf16(ah3, bfrag[G][4], a##G);

// lane's batch (= quad) C-element of gate G
#define SEL(G) ((quad & 2) ? ((quad & 1) ? a##G[3] : a##G[2])                 \
                           : ((quad & 1) ? a##G[1] : a##G[0]))

#define ACT_I { float e = __builtin_amdgcn_exp2f(SEL(0));                     \
                ig = __builtin_amdgcn_rcpf(1.0f + e); }
#define ACT_F { float e = __builtin_amdgcn_exp2f(SEL(1));                     \
                fg = __builtin_amdgcn_rcpf(1.0f + e); }
#define ACT_G { float e = __builtin_amdgcn_exp2f(fminf(SEL(2), 126.0f));      \
                float r = __builtin_amdgcn_rcpf(1.0f + e);                    \
                float t0 = S2 * r; gg2 = t0 - t0 * e; }     /* tanh(g)*S2 */
#define ACT_O { float e = __builtin_amdgcn_exp2f(SEL(3));                     \
                og = __builtin_amdgcn_rcpf(1.0f + e); }

  for (int t = 0; t < NT; ++t) {
    const int rd = t & 1, wr = rd ^ 1;

    // h A-frags (row = l16&3; 4-lane same-address broadcast)
    bf16x8 ah0 = *(const bf16x8*)&hfrag[rd][0][quad][l16 & 3][0];
    bf16x8 ah1 = *(const bf16x8*)&hfrag[rd][1][quad][l16 & 3][0];
    bf16x8 ah2 = *(const bf16x8*)&hfrag[rd][2][quad][l16 & 3][0];
    bf16x8 ah3 = *(const bf16x8*)&hfrag[rd][3][quad][l16 & 3][0];

    float4_t a0, a1, a2, a3;
    float ig, fg, gg2, og;

    // Staggered gate order: mates {w, w+4} (SIMD = w%4) differ, so while
    // one wave stalls at its act's data dep, the mate's chain MFMAs feed
    // the matrix pipe. SB() pins the [chain][act] interleave.
    if (w & 4) {
      CHAIN(2) ACT_G SB();
      CHAIN(3) ACT_O SB();
      CHAIN(0) ACT_I SB();
      CHAIN(1) ACT_F
    } else {
      CHAIN(0) ACT_I SB();
      CHAIN(1) ACT_F SB();
      CHAIN(2) ACT_G SB();
      CHAIN(3) ACT_O
    }

    // x reload for t+1 (vmem; consumed next step, latency fully covered)
    if (t + 1 < NT)
      ax = *(const bf16x8*)(Xb + xoff);
    xoff += NP;

    // c-chain tail + h write
    cs = fg * cs + ig * gg2;                         // c * S2
    float ec = __builtin_amdgcn_exp2f(fminf(cs, 126.0f));
    float rc = __builtin_amdgcn_rcpf(1.0f + ec);
    float h = og * (rc - ec * rc);                   // o * tanh(c)
    hfrag[wr][kcp][q2][quad][jj] = (__bf16)h;

    // fused head (rotating wave; ah = h_{t-1} -> out[t-1])
    if (t > 0 && w == (t & 7)) {
      float4_t p0 = {bo, bo, bo, bo};
      float4_t p1 = {0.f, 0.f, 0.f, 0.f};
      p0 = mfma_bf16(ah0, wof[0], p0);
      p1 = mfma_bf16(ah2, wof[2], p1);
      p0 = mfma_bf16(ah1, wof[1], p0);
      p1 = mfma_bf16(ah3, wof[3], p1);
      float4_t po = p0 + p1;
      if (lane == 0) {   // quad 0: C rows 0..3 = batches 0..3
#pragma unroll
        for (int r = 0; r < 4; ++r)
          outp[(size_t)r*(NT*NP) + (t - 1)*NP] = po[r];
      }
    }

    BAR();  // lgkmcnt-only barrier
  }
#undef CHAIN
#undef SEL
#undef ACT_I
#undef ACT_F
#undef ACT_G
#undef ACT_O

  // ---- epilogue: head for t = NT-1 (h_{NT-1} is in hfrag[NT&1]) ----
  if (w == 0) {
    bf16x8 ahf[4];
#pragma unroll
    for (int kc = 0; kc < 4; ++kc)
      ahf[kc] = *(const bf16x8*)&hfrag[NT & 1][kc][quad][l16 & 3][0];
    float4_t p0 = {bo, bo, bo, bo};
    float4_t p1 = {0.f, 0.f, 0.f, 0.f};
    p0 = mfma_bf16(ahf[0], wof[0], p0);
    p1 = mfma_bf16(ahf[2], wof[2], p1);
    p0 = mfma_bf16(ahf[1], wof[1], p0);
    p1 = mfma_bf16(ahf[3], wof[3], p1);
    float4_t po = p0 + p1;
    if (lane == 0) {
#pragma unroll
      for (int r = 0; r < 4; ++r)
        outp[(size_t)r*(NT*NP) + (NT - 1)*NP] = po[r];
    }
  }
}

// ---------------------------------------------------------------------------
// Fallback (ws too small): R8 kernel verbatim — M=4 / 256 blocks, fused
// head, f32 X loads, 219us rocprof. No workspace use.
// ---------------------------------------------------------------------------
__global__ __launch_bounds__(512, 1) void clstm_fused_fb(
    const float* __restrict__ X, const float* __restrict__ Wih,
    const float* __restrict__ Whh, const float* __restrict__ bih,
    const float* __restrict__ bhh, const float* __restrict__ Wout,
    const float* __restrict__ bout, float* __restrict__ out)
{
  const int net = blockIdx.x >> 3, bq = blockIdx.x & 7;
  const int tid = threadIdx.x;
  const int w = tid >> 6, lane = tid & 63;
  const int quad = lane >> 4, l16 = lane & 15;

  __shared__ __bf16 hfrag[2][4][4][4][8];
  { ((int*)hfrag)[tid] = 0; }
  __syncthreads();

  bf16x8 bfrag[4][5];
  float4_t bias4[4];
#pragma unroll
  for (int g = 0; g < 4; ++g) {
    const float scale = (g == 2) ? (-2.0f*LOG2E) : (-LOG2E);
    const int col = g*NH + w*16 + l16;
#pragma unroll
    for (int kc = 0; kc < 5; ++kc) {
      const float* src = (kc == 0) ? (Wih + ((size_t)net*FH + col)*NP + quad*8)
                                   : (Whh + ((size_t)net*FH + col)*NH + (kc-1)*32 + quad*8);
      bf16x8 bf;
#pragma unroll
      for (int j = 0; j < 8; ++j) bf[j] = (__bf16)(src[j] * scale);
      bfrag[g][kc] = bf;
    }
    const float b = (bih[net*FH + col] + bhh[net*FH + col]) * scale;
    bias4[g] = (float4_t){b, b, b, b};
  }

  bf16x8 wof[4];
#pragma unroll
  for (int kc = 0; kc < 4; ++kc) {
    const float* wp = Wout + net*NH + kc*32 + quad*8;
#pragma unroll
    for (int j = 0; j < 8; ++j) wof[kc][j] = (__bf16)wp[j];
  }
  const float bo = bout[net];

  float cs = 0.f;
  const float S2 = -2.0f*LOG2E;

  const float* xrow = X + (size_t)(bq*4 + (l16 & 3))*(NT*NP) + quad*8;
  const int kcp = w >> 1, q2 = ((w & 1) << 1) | (l16 >> 3), jj = l16 & 7;
  float* outp = out + ((size_t)bq*4)*(NT*NP) + net;

  bf16x8 ax;
  {
    float xv0[8];
    *(float4_t*)&xv0[0] = *(const float4_t*)xrow;
    *(float4_t*)&xv0[4] = *(const float4_t*)(xrow + 4);
#pragma unroll
    for (int j = 0; j < 8; ++j) ax[j] = (__bf16)xv0[j];
  }
  const float* xp = xrow + NP;
  float xv[8] = {0.f,0.f,0.f,0.f,0.f,0.f,0.f,0.f};

  for (int t = 0; t < NT; ++t) {
    const int rd = t & 1, wr = rd ^ 1;
    bf16x8 ah[4];
#pragma unroll
    for (int kc = 0; kc < 4; ++kc)
      ah[kc] = *(const bf16x8*)&hfrag[rd][kc][quad][l16 & 3][0];
    float4_t accx[4];
#pragma unroll
    for (int g = 0; g < 4; ++g)
      accx[g] = mfma_bf16(ax, bfrag[g][0], bias4[g]);
    if (t + 1 < NT) {
      *(float4_t*)&xv[0] = *(const float4_t*)xp;
      *(float4_t*)&xv[4] = *(const float4_t*)(xp + 4);
    }
    float4_t acc[4];
#pragma unroll
    for (int g = 0; g < 4; ++g) {
      float4_t a0 = mfma_bf16(ah[0], bfrag[g][1], accx[g]);
      float4_t a1 = mfma_bf16(ah[2], bfrag[g][3], (float4_t){0.f,0.f,0.f,0.f});
      a0 = mfma_bf16(ah[1], bfrag[g][2], a0);
      a1 = mfma_bf16(ah[3], bfrag[g][4], a1);
      acc[g] = a0 + a1;
    }
    float gv[4];
#pragma unroll
    for (int g = 0; g < 4; ++g) {
      float a01 = (quad & 1) ? acc[g][1] : acc[g][0];
      float a23 = (quad & 1) ? acc[g][3] : acc[g][2];
      gv[g] = (quad & 2) ? a23 : a01;
    }
    float h;
    {
      float ei = __builtin_amdgcn_exp2f(gv[0]);
      float ig = __builtin_amdgcn_rcpf(1.0f + ei);
      float ef = __builtin_amdgcn_exp2f(gv[1]);
      float fg = __builtin_amdgcn_rcpf(1.0f + ef);
      float eg = __builtin_amdgcn_exp2f(fminf(gv[2], 126.0f));
      float rg = __builtin_amdgcn_rcpf(1.0f + eg);
      float t0 = S2 * rg;
      float gg2 = t0 - t0 * eg;
      float eo = __builtin_amdgcn_exp2f(gv[3]);
      float og = __builtin_amdgcn_rcpf(1.0f + eo);
      cs = fg * cs + ig * gg2;
      float ec = __builtin_amdgcn_exp2f(fminf(cs, 126.0f));
      float rc = __builtin_amdgcn_rcpf(1.0f + ec);
      float th = rc - ec * rc;
      h = og * th;
    }
    hfrag[wr][kcp][q2][quad][jj] = (__bf16)h;
    if (w == 0 && t > 0) {
      float4_t p0 = {bo, bo, bo, bo};
      float4_t p1 = {0.f, 0.f, 0.f, 0.f};
      p0 = mfma_bf16(ah[0], wof[0], p0);
      p1 = mfma_bf16(ah[2], wof[2], p1);
      p0 = mfma_bf16(ah[1], wof[1], p0);
      p1 = mfma_bf16(ah[3], wof[3], p1);
      float4_t po = p0 + p1;
      if (lane == 0) {
#pragma unroll
        for (int r = 0; r < 4; ++r)
          outp[(size_t)r*(NT*NP) + (t - 1)*NP] = po[r];
      }
    }
#pragma unroll
    for (int j = 0; j < 8; ++j) ax[j] = (__bf16)xv[j];
    xp += NP;
    BAR();
  }

  if (w == 0) {
    bf16x8 ahf[4];
#pragma unroll
    for (int kc = 0; kc < 4; ++kc)
      ahf[kc] = *(const bf16x8*)&hfrag[NT & 1][kc][quad][l16 & 3][0];
    float4_t p0 = {bo, bo, bo, bo};
    float4_t p1 = {0.f, 0.f, 0.f, 0.f};
    p0 = mfma_bf16(ahf[0], wof[0], p0);
    p1 = mfma_bf16(ahf[2], wof[2], p1);
    p0 = mfma_bf16(ahf[1], wof[1], p0);
    p1 = mfma_bf16(ahf[3], wof[3], p1);
    float4_t po = p0 + p1;
    if (lane == 0) {
#pragma unroll
      for (int r = 0; r < 4; ++r)
        outp[(size_t)r*(NT*NP) + (NT - 1)*NP] = po[r];
    }
  }
}

extern "C" void kernel_launch(void* const* d_in, const int* in_sizes, int n_in,
                              void* d_out, int out_size, void* d_ws, size_t ws_size,
                              hipStream_t stream) {
  const float* X    = (const float*)d_in[0];
  const float* Wih  = (const float*)d_in[1];
  const float* Whh  = (const float*)d_in[2];
  const float* bih  = (const float*)d_in[3];
  const float* bhh  = (const float*)d_in[4];
  const float* Wout = (const float*)d_in[5];
  const float* bout = (const float*)d_in[6];
  float* out = (float*)d_out;
  (void)in_sizes; (void)n_in; (void)out_size;

  // ws layout: [0, 512KB) X as bf16.
  const size_t need = (size_t)NB*NT*NP*2;
  if (d_ws != nullptr && ws_size >= need) {
    __bf16* wsX = (__bf16*)d_ws;
    xcvt<<<128, 512, 0, stream>>>(X, wsX);
    // 256 blocks = 32 nets x 8 batch-groups (M=4); XCD-swizzled net map;
    // 1 block/CU; 256-reg budget via waves_per_eu(2,2).
    clstm_fused5<<<256, 512, 0, stream>>>(wsX, Wih, Whh, bih, bhh, Wout,
                                          bout, out);
  } else {
    // R8 fallback: no workspace required.
    clstm_fused_fb<<<256, 512, 0, stream>>>(X, Wih, Whh, bih, bhh, Wout,
                                            bout, out);
  }
}

// Round 10
// 213.083 us; speedup vs baseline: 1.0993x; 1.0993x over previous
//
#include <hip/hip_runtime.h>
#include <stdint.h>

// Problem constants (match reference)
#define NP 32    // num networks (P)
#define NH 128   // hidden (H)
#define NB 32    // batch (B)
#define NT 256   // time (T)
#define FH 512   // 4*H

typedef __attribute__((ext_vector_type(4))) float float4_t;
typedef __attribute__((ext_vector_type(8))) __bf16 bf16x8;
typedef __attribute__((ext_vector_type(4))) __bf16 bf16x4;

static __device__ __forceinline__ float4_t mfma_bf16(bf16x8 a, bf16x8 b, float4_t c) {
  return __builtin_amdgcn_mfma_f32_16x16x32_bf16(a, b, c, 0, 0, 0);
}

#define LOG2E 1.4426950408889634f

// Raw workgroup barrier: drains LDS ops only (cross-wave h visibility), does
// NOT drain vmcnt — pending global loads/stores stay in flight across it.
#define BAR() __asm__ volatile("s_waitcnt lgkmcnt(0)\n\ts_barrier" ::: "memory")

// ---------------------------------------------------------------------------
// R18: back to R15's chain structure (best, 163us) + pure instruction wins.
// R17 post-mortem: SB-segmented stagger carved 1-ILP segments (one 5-deep
// dependent chain each) -> exposed MFMA dep latency -> 180us. XCD swizzle
// DID work (FETCH 42->7.3MB) — kept. Session pattern: instruction-reduction
// rounds win (R15 -25%), schedule/overlap rounds lose (R14/R16/R17). R14's
// "issue-bound" read was confounded: M=2 dup waste exactly cancels any
// co-residency gain (checked again for 4-wave/512-block: same cancellation).
// Full-chip M=4 / 8-wave / 1 block/CU is geometrically forced.
// New cuts:
//  - DUP-GROUPED A-ROWS: row r -> batch r>>2 (was r&3). Lane-quad q's four
//    C regs = rows 4q..4q+3 = batch q x4 dup -> gv = acc[0], NO cndmask
//    select (-12/step). Head store becomes per-quad po[0] (l16==0 lanes).
//    Write-side unchanged (lane batch still = quad); read row = l16>>2.
//  - unroll x2: literal rd/wr, LDS offsets fold to immediates.
//  - pre-BAR x-MFMA(t+1) issue (ax=x(t+1) loaded mid-step; no LDS dep):
//    matrix pipe carries ~155cyc backlog across barrier+ds_read window.
//  - no sched_barrier anywhere (compiler schedules; R16/R17 evidence).
// SESSION RULES: launch_bounds 2nd arg never !=1 (R9-R11 spill death);
// waves_per_eu(2,2) is the trusted 256-reg knob (R15); no DS ops in loop
// beyond h write/read (R5); M=2-based co-residency arithmetically dead
// (R14); SB around dependent chains kills ILP (R17).
// ---------------------------------------------------------------------------

// Prepass: X f32 -> bf16 into ws (same [B][T][P] layout). 262144 elems.
__global__ __launch_bounds__(512, 1) void xcvt(
    const float* __restrict__ X, __bf16* __restrict__ Xb)
{
  const int i = (blockIdx.x * 512 + threadIdx.x) * 4;
  float4_t v = *(const float4_t*)(X + i);
  bf16x4 o;
#pragma unroll
  for (int j = 0; j < 4; ++j) o[j] = (__bf16)v[j];
  *(bf16x4*)(Xb + i) = o;
}

__global__ __attribute__((amdgpu_flat_work_group_size(512, 512),
                          amdgpu_waves_per_eu(2, 2)))
void clstm_fused6(
    const __bf16* __restrict__ Xb, const float* __restrict__ Wih,
    const float* __restrict__ Whh, const float* __restrict__ bih,
    const float* __restrict__ bhh, const float* __restrict__ Wout,
    const float* __restrict__ bout, float* __restrict__ out)
{
  // XCD swizzle (R17-proven): blocks {n, n+32, ...} share net n and land on
  // one XCD -> weights L2-resident. FETCH 42->7.3MB.
  const int net = blockIdx.x & 31, bq = blockIdx.x >> 5;
  const int tid = threadIdx.x;
  const int w = tid >> 6, lane = tid & 63;
  const int quad = lane >> 4, l16 = lane & 15;

  // h A-fragments, double buffered, 4 DISTINCT rows: [buf][kc][kquad][m<4][j]
  __shared__ __bf16 hfrag[2][4][4][4][8];   // 2 KB total

  { ((int*)hfrag)[tid] = 0; }   // h0 = 0, both buffers
  __syncthreads();

  // ---- load weights into register B-fragments (one-time) ----
  // B-frag layout for 16x16x32: lane holds B[k = quad*8 + j][n = l16].
  bf16x8 bfrag[4][5];
  float4_t bias4[4];
#pragma unroll
  for (int g = 0; g < 4; ++g) {
    const float scale = (g == 2) ? (-2.0f*LOG2E) : (-LOG2E);
    const int col = g*NH + w*16 + l16;
#pragma unroll
    for (int kc = 0; kc < 5; ++kc) {
      const float* src = (kc == 0) ? (Wih + ((size_t)net*FH + col)*NP + quad*8)
                                   : (Whh + ((size_t)net*FH + col)*NH + (kc-1)*32 + quad*8);
      bf16x8 bf;
#pragma unroll
      for (int j = 0; j < 8; ++j) bf[j] = (__bf16)(src[j] * scale);
      bfrag[g][kc] = bf;
    }
    const float b = (bih[net*FH + col] + bhh[net*FH + col]) * scale;
    bias4[g] = (float4_t){b, b, b, b};
  }

  // head B-frags (all waves — head rotates): B[k][n] = wout[k] broadcast.
  bf16x8 wof[4];
#pragma unroll
  for (int kc = 0; kc < 4; ++kc) {
    const float* wp = Wout + net*NH + kc*32 + quad*8;
#pragma unroll
    for (int j = 0; j < 8; ++j) wof[kc][j] = (__bf16)wp[j];
  }
  const float bo = bout[net];

  // c state, PRE-SCALED by -2log2e (saves a mul on the h critical chain)
  float cs = 0.f;
  const float S2 = -2.0f*LOG2E;

  // x source: A-row l16 -> batch bq*4 + (l16>>2)  (DUP-GROUPED rows)
  int xoff = (bq*4 + (l16 >> 2))*(NT*NP) + quad*8;

  // h write coords for unit u = w*16 + l16; batch row = quad (unchanged)
  const int kcp = w >> 1, q2 = ((w & 1) << 1) | (l16 >> 3), jj = l16 & 7;

  // head store base: out[(bq*4 + quad)*NT*NP + t*NP + net], stored by the
  // rotating head wave's lanes with l16==0 (C rows 4q.. = batch q dup).
  float* outp = out + ((size_t)(bq*4 + quad))*(NT*NP) + net;

  // prologue: ax = x(0); pre-issue x-MFMAs for t=0 (C = bias)
  bf16x8 ax = *(const bf16x8*)(Xb + xoff);
  xoff += NP;
  float4_t a0 = mfma_bf16(ax, bfrag[0][0], bias4[0]);
  float4_t a1 = mfma_bf16(ax, bfrag[1][0], bias4[1]);
  float4_t a2 = mfma_bf16(ax, bfrag[2][0], bias4[2]);
  float4_t a3 = mfma_bf16(ax, bfrag[3][0], bias4[3]);

// ---- one step; RD/WR literal (unroll x2). a0..a3 enter holding the
// pre-issued x-MFMA results (xproj + bias) for step T_. ----
#define STEP(RD, WR, T_)                                                      \
  do {                                                                        \
    /* h A-frags (row = l16>>2; 4-lane same-address broadcast) */             \
    bf16x8 ah0 = *(const bf16x8*)&hfrag[RD][0][quad][l16 >> 2][0];            \
    bf16x8 ah1 = *(const bf16x8*)&hfrag[RD][1][quad][l16 >> 2][0];            \
    bf16x8 ah2 = *(const bf16x8*)&hfrag[RD][2][quad][l16 >> 2][0];            \
    bf16x8 ah3 = *(const bf16x8*)&hfrag[RD][3][quad][l16 >> 2][0];            \
    /* h-MFMAs: 4 serial chains (depth 4 here; x-root issued last step) */    \
    a0 = mfma_bf16(ah0, bfrag[0][1], a0);                                     \
    a1 = mfma_bf16(ah0, bfrag[1][1], a1);                                     \
    a2 = mfma_bf16(ah0, bfrag[2][1], a2);                                     \
    a3 = mfma_bf16(ah0, bfrag[3][1], a3);                                     \
    a0 = mfma_bf16(ah1, bfrag[0][2], a0);                                     \
    a1 = mfma_bf16(ah1, bfrag[1][2], a1);                                     \
    a2 = mfma_bf16(ah1, bfrag[2][2], a2);                                     \
    a3 = mfma_bf16(ah1, bfrag[3][2], a3);                                     \
    a0 = mfma_bf16(ah2, bfrag[0][3], a0);                                     \
    a1 = mfma_bf16(ah2, bfrag[1][3], a1);                                     \
    a2 = mfma_bf16(ah2, bfrag[2][3], a2);                                     \
    a3 = mfma_bf16(ah2, bfrag[3][3], a3);                                     \
    a0 = mfma_bf16(ah3, bfrag[0][4], a0);                                     \
    a1 = mfma_bf16(ah3, bfrag[1][4], a1);                                     \
    a2 = mfma_bf16(ah3, bfrag[2][4], a2);                                     \
    a3 = mfma_bf16(ah3, bfrag[3][4], a3);                                     \
    /* x reload for t+1 (guarded; ax dead — consumed by last step's tail) */  \
    if ((T_) + 1 < NT)                                                        \
      ax = *(const bf16x8*)(Xb + xoff);                                       \
    xoff += NP;                                                               \
    /* acts: gv = acc[0] (dup-grouped rows — NO cndmask select) */            \
    float ei = __builtin_amdgcn_exp2f(a0[0]);                                 \
    float ig = __builtin_amdgcn_rcpf(1.0f + ei);          /* sigmoid(i) */    \
    float ef = __builtin_amdgcn_exp2f(a1[0]);                                 \
    float fg = __builtin_amdgcn_rcpf(1.0f + ef);          /* sigmoid(f) */    \
    float eg = __builtin_amdgcn_exp2f(fminf(a2[0], 126.0f));                  \
    float rg = __builtin_amdgcn_rcpf(1.0f + eg);                              \
    float t0 = S2 * rg;                                                       \
    float gg2 = t0 - t0 * eg;                             /* tanh(g)*S2 */    \
    float eo = __builtin_amdgcn_exp2f(a3[0]);                                 \
    float og = __builtin_amdgcn_rcpf(1.0f + eo);          /* sigmoid(o) */    \
    cs = fg * cs + ig * gg2;                              /* c * S2 */        \
    float ec = __builtin_amdgcn_exp2f(fminf(cs, 126.0f));                     \
    float rc = __builtin_amdgcn_rcpf(1.0f + ec);                              \
    float h_ = og * (rc - ec * rc);                       /* o*tanh(c) */     \
    /* write h' (bf16): 1 ds_write_b16, batch row = quad */                   \
    hfrag[WR][kcp][q2][quad][jj] = (__bf16)h_;                                \
    /* rotating fused head (ah = h_{t-1} -> out[t-1]); per-quad store */      \
    if ((T_) > 0 && w == ((T_) & 7)) {                                        \
      float4_t p0 = {bo, bo, bo, bo};                                         \
      float4_t p1 = {0.f, 0.f, 0.f, 0.f};                                     \
      p0 = mfma_bf16(ah0, wof[0], p0);                                        \
      p1 = mfma_bf16(ah2, wof[2], p1);                                        \
      p0 = mfma_bf16(ah1, wof[1], p0);                                        \
      p1 = mfma_bf16(ah3, wof[3], p1);                                        \
      if (l16 == 0)                                                           \
        outp[(size_t)((T_) - 1)*NP] = p0[0] + p1[0];                          \
    }                                                                         \
    /* pre-issue x-MFMAs for t+1 (pipe backlog across BAR+ds window) */       \
    a0 = mfma_bf16(ax, bfrag[0][0], bias4[0]);                                \
    a1 = mfma_bf16(ax, bfrag[1][0], bias4[1]);                                \
    a2 = mfma_bf16(ax, bfrag[2][0], bias4[2]);                                \
    a3 = mfma_bf16(ax, bfrag[3][0], bias4[3]);                                \
    BAR();                                                                    \
  } while (0)

  for (int t = 0; t < NT; t += 2) {
    STEP(0, 1, t);
    STEP(1, 0, t + 1);
  }
#undef STEP

  // ---- epilogue: head for t = NT-1 (h_{NT-1} is in hfrag[NT&1]) ----
  if (w == 0) {
    bf16x8 ahf[4];
#pragma unroll
    for (int kc = 0; kc < 4; ++kc)
      ahf[kc] = *(const bf16x8*)&hfrag[NT & 1][kc][quad][l16 >> 2][0];
    float4_t p0 = {bo, bo, bo, bo};
    float4_t p1 = {0.f, 0.f, 0.f, 0.f};
    p0 = mfma_bf16(ahf[0], wof[0], p0);
    p1 = mfma_bf16(ahf[2], wof[2], p1);
    p0 = mfma_bf16(ahf[1], wof[1], p0);
    p1 = mfma_bf16(ahf[3], wof[3], p1);
    if (l16 == 0)
      outp[(size_t)(NT - 1)*NP] = p0[0] + p1[0];
  }
}

// ---------------------------------------------------------------------------
// Fallback (ws too small): R8 kernel verbatim — M=4 / 256 blocks, fused
// head, f32 X loads, 219us rocprof. No workspace use.
// ---------------------------------------------------------------------------
__global__ __launch_bounds__(512, 1) void clstm_fused_fb(
    const float* __restrict__ X, const float* __restrict__ Wih,
    const float* __restrict__ Whh, const float* __restrict__ bih,
    const float* __restrict__ bhh, const float* __restrict__ Wout,
    const float* __restrict__ bout, float* __restrict__ out)
{
  const int net = blockIdx.x >> 3, bq = blockIdx.x & 7;
  const int tid = threadIdx.x;
  const int w = tid >> 6, lane = tid & 63;
  const int quad = lane >> 4, l16 = lane & 15;

  __shared__ __bf16 hfrag[2][4][4][4][8];
  { ((int*)hfrag)[tid] = 0; }
  __syncthreads();

  bf16x8 bfrag[4][5];
  float4_t bias4[4];
#pragma unroll
  for (int g = 0; g < 4; ++g) {
    const float scale = (g == 2) ? (-2.0f*LOG2E) : (-LOG2E);
    const int col = g*NH + w*16 + l16;
#pragma unroll
    for (int kc = 0; kc < 5; ++kc) {
      const float* src = (kc == 0) ? (Wih + ((size_t)net*FH + col)*NP + quad*8)
                                   : (Whh + ((size_t)net*FH + col)*NH + (kc-1)*32 + quad*8);
      bf16x8 bf;
#pragma unroll
      for (int j = 0; j < 8; ++j) bf[j] = (__bf16)(src[j] * scale);
      bfrag[g][kc] = bf;
    }
    const float b = (bih[net*FH + col] + bhh[net*FH + col]) * scale;
    bias4[g] = (float4_t){b, b, b, b};
  }

  bf16x8 wof[4];
#pragma unroll
  for (int kc = 0; kc < 4; ++kc) {
    const float* wp = Wout + net*NH + kc*32 + quad*8;
#pragma unroll
    for (int j = 0; j < 8; ++j) wof[kc][j] = (__bf16)wp[j];
  }
  const float bo = bout[net];

  float cs = 0.f;
  const float S2 = -2.0f*LOG2E;

  const float* xrow = X + (size_t)(bq*4 + (l16 & 3))*(NT*NP) + quad*8;
  const int kcp = w >> 1, q2 = ((w & 1) << 1) | (l16 >> 3), jj = l16 & 7;
  float* outp = out + ((size_t)bq*4)*(NT*NP) + net;

  bf16x8 ax;
  {
    float xv0[8];
    *(float4_t*)&xv0[0] = *(const float4_t*)xrow;
    *(float4_t*)&xv0[4] = *(const float4_t*)(xrow + 4);
#pragma unroll
    for (int j = 0; j < 8; ++j) ax[j] = (__bf16)xv0[j];
  }
  const float* xp = xrow + NP;
  float xv[8] = {0.f,0.f,0.f,0.f,0.f,0.f,0.f,0.f};

  for (int t = 0; t < NT; ++t) {
    const int rd = t & 1, wr = rd ^ 1;
    bf16x8 ah[4];
#pragma unroll
    for (int kc = 0; kc < 4; ++kc)
      ah[kc] = *(const bf16x8*)&hfrag[rd][kc][quad][l16 & 3][0];
    float4_t accx[4];
#pragma unroll
    for (int g = 0; g < 4; ++g)
      accx[g] = mfma_bf16(ax, bfrag[g][0], bias4[g]);
    if (t + 1 < NT) {
      *(float4_t*)&xv[0] = *(const float4_t*)xp;
      *(float4_t*)&xv[4] = *(const float4_t*)(xp + 4);
    }
    float4_t acc[4];
#pragma unroll
    for (int g = 0; g < 4; ++g) {
      float4_t a0 = mfma_bf16(ah[0], bfrag[g][1], accx[g]);
      float4_t a1 = mfma_bf16(ah[2], bfrag[g][3], (float4_t){0.f,0.f,0.f,0.f});
      a0 = mfma_bf16(ah[1], bfrag[g][2], a0);
      a1 = mfma_bf16(ah[3], bfrag[g][4], a1);
      acc[g] = a0 + a1;
    }
    float gv[4];
#pragma unroll
    for (int g = 0; g < 4; ++g) {
      float a01 = (quad & 1) ? acc[g][1] : acc[g][0];
      float a23 = (quad & 1) ? acc[g][3] : acc[g][2];
      gv[g] = (quad & 2) ? a23 : a01;
    }
    float h;
    {
      float ei = __builtin_amdgcn_exp2f(gv[0]);
      float ig = __builtin_amdgcn_rcpf(1.0f + ei);
      float ef = __builtin_amdgcn_exp2f(gv[1]);
      float fg = __builtin_amdgcn_rcpf(1.0f + ef);
      float eg = __builtin_amdgcn_exp2f(fminf(gv[2], 126.0f));
      float rg = __builtin_amdgcn_rcpf(1.0f + eg);
      float t0 = S2 * rg;
      float gg2 = t0 - t0 * eg;
      float eo = __builtin_amdgcn_exp2f(gv[3]);
      float og = __builtin_amdgcn_rcpf(1.0f + eo);
      cs = fg * cs + ig * gg2;
      float ec = __builtin_amdgcn_exp2f(fminf(cs, 126.0f));
      float rc = __builtin_amdgcn_rcpf(1.0f + ec);
      float th = rc - ec * rc;
      h = og * th;
    }
    hfrag[wr][kcp][q2][quad][jj] = (__bf16)h;
    if (w == 0 && t > 0) {
      float4_t p0 = {bo, bo, bo, bo};
      float4_t p1 = {0.f, 0.f, 0.f, 0.f};
      p0 = mfma_bf16(ah[0], wof[0], p0);
      p1 = mfma_bf16(ah[2], wof[2], p1);
      p0 = mfma_bf16(ah[1], wof[1], p0);
      p1 = mfma_bf16(ah[3], wof[3], p1);
      float4_t po = p0 + p1;
      if (lane == 0) {
#pragma unroll
        for (int r = 0; r < 4; ++r)
          outp[(size_t)r*(NT*NP) + (t - 1)*NP] = po[r];
      }
    }
#pragma unroll
    for (int j = 0; j < 8; ++j) ax[j] = (__bf16)xv[j];
    xp += NP;
    BAR();
  }

  if (w == 0) {
    bf16x8 ahf[4];
#pragma unroll
    for (int kc = 0; kc < 4; ++kc)
      ahf[kc] = *(const bf16x8*)&hfrag[NT & 1][kc][quad][l16 & 3][0];
    float4_t p0 = {bo, bo, bo, bo};
    float4_t p1 = {0.f, 0.f, 0.f, 0.f};
    p0 = mfma_bf16(ahf[0], wof[0], p0);
    p1 = mfma_bf16(ahf[2], wof[2], p1);
    p0 = mfma_bf16(ahf[1], wof[1], p0);
    p1 = mfma_bf16(ahf[3], wof[3], p1);
    float4_t po = p0 + p1;
    if (lane == 0) {
#pragma unroll
      for (int r = 0; r < 4; ++r)
        outp[(size_t)r*(NT*NP) + (NT - 1)*NP] = po[r];
    }
  }
}

extern "C" void kernel_launch(void* const* d_in, const int* in_sizes, int n_in,
                              void* d_out, int out_size, void* d_ws, size_t ws_size,
                              hipStream_t stream) {
  const float* X    = (const float*)d_in[0];
  const float* Wih  = (const float*)d_in[1];
  const float* Whh  = (const float*)d_in[2];
  const float* bih  = (const float*)d_in[3];
  const float* bhh  = (const float*)d_in[4];
  const float* Wout = (const float*)d_in[5];
  const float* bout = (const float*)d_in[6];
  float* out = (float*)d_out;
  (void)in_sizes; (void)n_in; (void)out_size;

  // ws layout: [0, 512KB) X as bf16.
  const size_t need = (size_t)NB*NT*NP*2;
  if (d_ws != nullptr && ws_size >= need) {
    __bf16* wsX = (__bf16*)d_ws;
    xcvt<<<128, 512, 0, stream>>>(X, wsX);
    // 256 blocks = 32 nets (XCD-swizzled) x 8 batch-groups (M=4);
    // 1 block/CU; 256-reg budget via waves_per_eu(2,2).
    clstm_fused6<<<256, 512, 0, stream>>>(wsX, Wih, Whh, bih, bhh, Wout,
                                          bout, out);
  } else {
    // R8 fallback: no workspace required.
    clstm_fused_fb<<<256, 512, 0, stream>>>(X, Wih, Whh, bih, bhh, Wout,
                                            bout, out);
  }
}

// Round 11
// 207.201 us; speedup vs baseline: 1.1305x; 1.0284x over previous
//
#include <hip/hip_runtime.h>
#include <stdint.h>

// Problem constants (match reference)
#define NP 32    // num networks (P)
#define NH 128   // hidden (H)
#define NB 32    // batch (B)
#define NT 256   // time (T)
#define FH 512   // 4*H

typedef __attribute__((ext_vector_type(4))) float float4_t;
typedef __attribute__((ext_vector_type(8))) __bf16 bf16x8;
typedef __attribute__((ext_vector_type(4))) __bf16 bf16x4;

static __device__ __forceinline__ float4_t mfma_bf16(bf16x8 a, bf16x8 b, float4_t c) {
  return __builtin_amdgcn_mfma_f32_16x16x32_bf16(a, b, c, 0, 0, 0);
}

#define LOG2E 1.4426950408889634f

// Raw workgroup barrier: drains LDS ops only (cross-wave h visibility), does
// NOT drain vmcnt — pending global loads/stores stay in flight across it.
#define BAR() __asm__ volatile("s_waitcnt lgkmcnt(0)\n\ts_barrier" ::: "memory")

// ---------------------------------------------------------------------------
// R19: R15's schedule + R18's instruction cuts (the clean union).
// R18 post-mortem: pre-issuing x-MFMAs before BAR moved the ax consumption
// into the SAME step's tail -> x-load shadow shrank from ~400+ cyc (R15:
// consumed next-step-top) to ~150 cyc < L2 latency -> vmcnt stall on the
// critical path, 163->170us. The VALU cuts themselves landed (VALUBusy
// 42.6->32.0) with ~zero dur effect -> VALU issue has slack; step is
// pipe(776) + serial latency + haze, additive.
// R19 keeps from R18: dup-grouped A-rows (row r -> batch r>>2; gv = acc[0],
// no cndmask select), unroll x2 literal rd/wr, XCD net swizzle (FETCH
// 42->7.3MB), rotating head with per-quad po[0] store.
// R19 restores from R15: x-MFMAs at step TOP as chain roots (C=bias4);
// ax(t+1) loaded right after, consumed NEXT step (full ~1100cyc shadow);
// nothing issued between head and BAR.
// SESSION RULES: launch_bounds 2nd arg never !=1 (R9-R11 spill death);
// waves_per_eu(2,2) is the trusted 256-reg knob (R15); no DS ops in loop
// beyond h write/read (R5); M=4/256 blocks geometrically forced (R12/R14);
// overlap via co-residency (R14), SB-stagger (R17), mid-chain act segments
// (R16), pre-BAR x-MFMA (R18) all refuted — instruction/shadow discipline
// is the only lever that has ever won (R15: -25%).
// ---------------------------------------------------------------------------

// Prepass: X f32 -> bf16 into ws (same [B][T][P] layout). 262144 elems.
__global__ __launch_bounds__(512, 1) void xcvt(
    const float* __restrict__ X, __bf16* __restrict__ Xb)
{
  const int i = (blockIdx.x * 512 + threadIdx.x) * 4;
  float4_t v = *(const float4_t*)(X + i);
  bf16x4 o;
#pragma unroll
  for (int j = 0; j < 4; ++j) o[j] = (__bf16)v[j];
  *(bf16x4*)(Xb + i) = o;
}

__global__ __attribute__((amdgpu_flat_work_group_size(512, 512),
                          amdgpu_waves_per_eu(2, 2)))
void clstm_fused7(
    const __bf16* __restrict__ Xb, const float* __restrict__ Wih,
    const float* __restrict__ Whh, const float* __restrict__ bih,
    const float* __restrict__ bhh, const float* __restrict__ Wout,
    const float* __restrict__ bout, float* __restrict__ out)
{
  // XCD swizzle (R17-proven): blocks {n, n+32, ...} share net n and land on
  // one XCD -> weights L2-resident.
  const int net = blockIdx.x & 31, bq = blockIdx.x >> 5;
  const int tid = threadIdx.x;
  const int w = tid >> 6, lane = tid & 63;
  const int quad = lane >> 4, l16 = lane & 15;

  // h A-fragments, double buffered, 4 DISTINCT rows: [buf][kc][kquad][m<4][j]
  __shared__ __bf16 hfrag[2][4][4][4][8];   // 2 KB total

  { ((int*)hfrag)[tid] = 0; }   // h0 = 0, both buffers
  __syncthreads();

  // ---- load weights into register B-fragments (one-time) ----
  // B-frag layout for 16x16x32: lane holds B[k = quad*8 + j][n = l16].
  bf16x8 bfrag[4][5];
  float4_t bias4[4];
#pragma unroll
  for (int g = 0; g < 4; ++g) {
    const float scale = (g == 2) ? (-2.0f*LOG2E) : (-LOG2E);
    const int col = g*NH + w*16 + l16;
#pragma unroll
    for (int kc = 0; kc < 5; ++kc) {
      const float* src = (kc == 0) ? (Wih + ((size_t)net*FH + col)*NP + quad*8)
                                   : (Whh + ((size_t)net*FH + col)*NH + (kc-1)*32 + quad*8);
      bf16x8 bf;
#pragma unroll
      for (int j = 0; j < 8; ++j) bf[j] = (__bf16)(src[j] * scale);
      bfrag[g][kc] = bf;
    }
    const float b = (bih[net*FH + col] + bhh[net*FH + col]) * scale;
    bias4[g] = (float4_t){b, b, b, b};
  }

  // head B-frags (all waves — head rotates): B[k][n] = wout[k] broadcast.
  bf16x8 wof[4];
#pragma unroll
  for (int kc = 0; kc < 4; ++kc) {
    const float* wp = Wout + net*NH + kc*32 + quad*8;
#pragma unroll
    for (int j = 0; j < 8; ++j) wof[kc][j] = (__bf16)wp[j];
  }
  const float bo = bout[net];

  // c state, PRE-SCALED by -2log2e (saves a mul on the h critical chain)
  float cs = 0.f;
  const float S2 = -2.0f*LOG2E;

  // x source: A-row l16 -> batch bq*4 + (l16>>2)  (dup-grouped rows)
  int xoff = (bq*4 + (l16 >> 2))*(NT*NP) + quad*8;

  // h write coords for unit u = w*16 + l16; batch row = quad (unchanged)
  const int kcp = w >> 1, q2 = ((w & 1) << 1) | (l16 >> 3), jj = l16 & 7;

  // head store base: out[(bq*4 + quad)*NT*NP + t*NP + net], stored by the
  // rotating head wave's lanes with l16==0 (C rows 4q.. = batch q dup).
  float* outp = out + ((size_t)(bq*4 + quad))*(NT*NP) + net;

  // prologue: ax = x(0)
  bf16x8 ax = *(const bf16x8*)(Xb + xoff);
  xoff += NP;

// ---- one step; RD/WR literal (unroll x2). ax enters holding x(T_);
// x(T_+1) is loaded mid-step and consumed at the NEXT step's top (full
// shadow: 16 h-MFMAs + acts + write + BAR + ds_reads). ----
#define STEP(RD, WR, T_)                                                      \
  do {                                                                        \
    /* h A-frags (row = l16>>2; 4-lane same-address broadcast) */             \
    bf16x8 ah0 = *(const bf16x8*)&hfrag[RD][0][quad][l16 >> 2][0];            \
    bf16x8 ah1 = *(const bf16x8*)&hfrag[RD][1][quad][l16 >> 2][0];            \
    bf16x8 ah2 = *(const bf16x8*)&hfrag[RD][2][quad][l16 >> 2][0];            \
    bf16x8 ah3 = *(const bf16x8*)&hfrag[RD][3][quad][l16 >> 2][0];            \
    /* x-MFMAs first: chain roots (C = bias), no LDS dep — fill ds wait */    \
    float4_t a0 = mfma_bf16(ax, bfrag[0][0], bias4[0]);                       \
    float4_t a1 = mfma_bf16(ax, bfrag[1][0], bias4[1]);                       \
    float4_t a2 = mfma_bf16(ax, bfrag[2][0], bias4[2]);                       \
    float4_t a3 = mfma_bf16(ax, bfrag[3][0], bias4[3]);                       \
    /* x reload for t+1 (guarded; ax dead after the roots above) */           \
    if ((T_) + 1 < NT)                                                        \
      ax = *(const bf16x8*)(Xb + xoff);                                       \
    xoff += NP;                                                               \
    /* h-MFMAs: 4 serial chains, round-robin (4-way ILP) */                   \
    a0 = mfma_bf16(ah0, bfrag[0][1], a0);                                     \
    a1 = mfma_bf16(ah0, bfrag[1][1], a1);                                     \
    a2 = mfma_bf16(ah0, bfrag[2][1], a2);                                     \
    a3 = mfma_bf16(ah0, bfrag[3][1], a3);                                     \
    a0 = mfma_bf16(ah1, bfrag[0][2], a0);                                     \
    a1 = mfma_bf16(ah1, bfrag[1][2], a1);                                     \
    a2 = mfma_bf16(ah1, bfrag[2][2], a2);                                     \
    a3 = mfma_bf16(ah1, bfrag[3][2], a3);                                     \
    a0 = mfma_bf16(ah2, bfrag[0][3], a0);                                     \
    a1 = mfma_bf16(ah2, bfrag[1][3], a1);                                     \
    a2 = mfma_bf16(ah2, bfrag[2][3], a2);                                     \
    a3 = mfma_bf16(ah2, bfrag[3][3], a3);                                     \
    a0 = mfma_bf16(ah3, bfrag[0][4], a0);                                     \
    a1 = mfma_bf16(ah3, bfrag[1][4], a1);                                     \
    a2 = mfma_bf16(ah3, bfrag[2][4], a2);                                     \
    a3 = mfma_bf16(ah3, bfrag[3][4], a3);                                     \
    /* acts: gv = acc[0] (dup-grouped rows — no cndmask select) */            \
    float ei = __builtin_amdgcn_exp2f(a0[0]);                                 \
    float ig = __builtin_amdgcn_rcpf(1.0f + ei);          /* sigmoid(i) */    \
    float ef = __builtin_amdgcn_exp2f(a1[0]);                                 \
    float fg = __builtin_amdgcn_rcpf(1.0f + ef);          /* sigmoid(f) */    \
    float eg = __builtin_amdgcn_exp2f(fminf(a2[0], 126.0f));                  \
    float rg = __builtin_amdgcn_rcpf(1.0f + eg);                              \
    float t0 = S2 * rg;                                                       \
    float gg2 = t0 - t0 * eg;                             /* tanh(g)*S2 */    \
    float eo = __builtin_amdgcn_exp2f(a3[0]);                                 \
    float og = __builtin_amdgcn_rcpf(1.0f + eo);          /* sigmoid(o) */    \
    cs = fg * cs + ig * gg2;                              /* c * S2 */        \
    float ec = __builtin_amdgcn_exp2f(fminf(cs, 126.0f));                     \
    float rc = __builtin_amdgcn_rcpf(1.0f + ec);                              \
    float h_ = og * (rc - ec * rc);                       /* o*tanh(c) */     \
    /* write h' (bf16): 1 ds_write_b16, batch row = quad */                   \
    hfrag[WR][kcp][q2][quad][jj] = (__bf16)h_;                                \
    /* rotating fused head (ah = h_{t-1} -> out[t-1]); per-quad store */      \
    if ((T_) > 0 && w == ((T_) & 7)) {                                        \
      float4_t p0 = {bo, bo, bo, bo};                                         \
      float4_t p1 = {0.f, 0.f, 0.f, 0.f};                                     \
      p0 = mfma_bf16(ah0, wof[0], p0);                                        \
      p1 = mfma_bf16(ah2, wof[2], p1);                                        \
      p0 = mfma_bf16(ah1, wof[1], p0);                                        \
      p1 = mfma_bf16(ah3, wof[3], p1);                                        \
      if (l16 == 0)                                                           \
        outp[(size_t)((T_) - 1)*NP] = p0[0] + p1[0];                          \
    }                                                                         \
    BAR();                                                                    \
  } while (0)

  for (int t = 0; t < NT; t += 2) {
    STEP(0, 1, t);
    STEP(1, 0, t + 1);
  }
#undef STEP

  // ---- epilogue: head for t = NT-1 (h_{NT-1} is in hfrag[NT&1]) ----
  if (w == 0) {
    bf16x8 ahf[4];
#pragma unroll
    for (int kc = 0; kc < 4; ++kc)
      ahf[kc] = *(const bf16x8*)&hfrag[NT & 1][kc][quad][l16 >> 2][0];
    float4_t p0 = {bo, bo, bo, bo};
    float4_t p1 = {0.f, 0.f, 0.f, 0.f};
    p0 = mfma_bf16(ahf[0], wof[0], p0);
    p1 = mfma_bf16(ahf[2], wof[2], p1);
    p0 = mfma_bf16(ahf[1], wof[1], p0);
    p1 = mfma_bf16(ahf[3], wof[3], p1);
    if (l16 == 0)
      outp[(size_t)(NT - 1)*NP] = p0[0] + p1[0];
  }
}

// ---------------------------------------------------------------------------
// Fallback (ws too small): R8 kernel verbatim — M=4 / 256 blocks, fused
// head, f32 X loads, 219us rocprof. No workspace use.
// ---------------------------------------------------------------------------
__global__ __launch_bounds__(512, 1) void clstm_fused_fb(
    const float* __restrict__ X, const float* __restrict__ Wih,
    const float* __restrict__ Whh, const float* __restrict__ bih,
    const float* __restrict__ bhh, const float* __restrict__ Wout,
    const float* __restrict__ bout, float* __restrict__ out)
{
  const int net = blockIdx.x >> 3, bq = blockIdx.x & 7;
  const int tid = threadIdx.x;
  const int w = tid >> 6, lane = tid & 63;
  const int quad = lane >> 4, l16 = lane & 15;

  __shared__ __bf16 hfrag[2][4][4][4][8];
  { ((int*)hfrag)[tid] = 0; }
  __syncthreads();

  bf16x8 bfrag[4][5];
  float4_t bias4[4];
#pragma unroll
  for (int g = 0; g < 4; ++g) {
    const float scale = (g == 2) ? (-2.0f*LOG2E) : (-LOG2E);
    const int col = g*NH + w*16 + l16;
#pragma unroll
    for (int kc = 0; kc < 5; ++kc) {
      const float* src = (kc == 0) ? (Wih + ((size_t)net*FH + col)*NP + quad*8)
                                   : (Whh + ((size_t)net*FH + col)*NH + (kc-1)*32 + quad*8);
      bf16x8 bf;
#pragma unroll
      for (int j = 0; j < 8; ++j) bf[j] = (__bf16)(src[j] * scale);
      bfrag[g][kc] = bf;
    }
    const float b = (bih[net*FH + col] + bhh[net*FH + col]) * scale;
    bias4[g] = (float4_t){b, b, b, b};
  }

  bf16x8 wof[4];
#pragma unroll
  for (int kc = 0; kc < 4; ++kc) {
    const float* wp = Wout + net*NH + kc*32 + quad*8;
#pragma unroll
    for (int j = 0; j < 8; ++j) wof[kc][j] = (__bf16)wp[j];
  }
  const float bo = bout[net];

  float cs = 0.f;
  const float S2 = -2.0f*LOG2E;

  const float* xrow = X + (size_t)(bq*4 + (l16 & 3))*(NT*NP) + quad*8;
  const int kcp = w >> 1, q2 = ((w & 1) << 1) | (l16 >> 3), jj = l16 & 7;
  float* outp = out + ((size_t)bq*4)*(NT*NP) + net;

  bf16x8 ax;
  {
    float xv0[8];
    *(float4_t*)&xv0[0] = *(const float4_t*)xrow;
    *(float4_t*)&xv0[4] = *(const float4_t*)(xrow + 4);
#pragma unroll
    for (int j = 0; j < 8; ++j) ax[j] = (__bf16)xv0[j];
  }
  const float* xp = xrow + NP;
  float xv[8] = {0.f,0.f,0.f,0.f,0.f,0.f,0.f,0.f};

  for (int t = 0; t < NT; ++t) {
    const int rd = t & 1, wr = rd ^ 1;
    bf16x8 ah[4];
#pragma unroll
    for (int kc = 0; kc < 4; ++kc)
      ah[kc] = *(const bf16x8*)&hfrag[rd][kc][quad][l16 & 3][0];
    float4_t accx[4];
#pragma unroll
    for (int g = 0; g < 4; ++g)
      accx[g] = mfma_bf16(ax, bfrag[g][0], bias4[g]);
    if (t + 1 < NT) {
      *(float4_t*)&xv[0] = *(const float4_t*)xp;
      *(float4_t*)&xv[4] = *(const float4_t*)(xp + 4);
    }
    float4_t acc[4];
#pragma unroll
    for (int g = 0; g < 4; ++g) {
      float4_t a0 = mfma_bf16(ah[0], bfrag[g][1], accx[g]);
      float4_t a1 = mfma_bf16(ah[2], bfrag[g][3], (float4_t){0.f,0.f,0.f,0.f});
      a0 = mfma_bf16(ah[1], bfrag[g][2], a0);
      a1 = mfma_bf16(ah[3], bfrag[g][4], a1);
      acc[g] = a0 + a1;
    }
    float gv[4];
#pragma unroll
    for (int g = 0; g < 4; ++g) {
      float a01 = (quad & 1) ? acc[g][1] : acc[g][0];
      float a23 = (quad & 1) ? acc[g][3] : acc[g][2];
      gv[g] = (quad & 2) ? a23 : a01;
    }
    float h;
    {
      float ei = __builtin_amdgcn_exp2f(gv[0]);
      float ig = __builtin_amdgcn_rcpf(1.0f + ei);
      float ef = __builtin_amdgcn_exp2f(gv[1]);
      float fg = __builtin_amdgcn_rcpf(1.0f + ef);
      float eg = __builtin_amdgcn_exp2f(fminf(gv[2], 126.0f));
      float rg = __builtin_amdgcn_rcpf(1.0f + eg);
      float t0 = S2 * rg;
      float gg2 = t0 - t0 * eg;
      float eo = __builtin_amdgcn_exp2f(gv[3]);
      float og = __builtin_amdgcn_rcpf(1.0f + eo);
      cs = fg * cs + ig * gg2;
      float ec = __builtin_amdgcn_exp2f(fminf(cs, 126.0f));
      float rc = __builtin_amdgcn_rcpf(1.0f + ec);
      float th = rc - ec * rc;
      h = og * th;
    }
    hfrag[wr][kcp][q2][quad][jj] = (__bf16)h;
    if (w == 0 && t > 0) {
      float4_t p0 = {bo, bo, bo, bo};
      float4_t p1 = {0.f, 0.f, 0.f, 0.f};
      p0 = mfma_bf16(ah[0], wof[0], p0);
      p1 = mfma_bf16(ah[2], wof[2], p1);
      p0 = mfma_bf16(ah[1], wof[1], p0);
      p1 = mfma_bf16(ah[3], wof[3], p1);
      float4_t po = p0 + p1;
      if (lane == 0) {
#pragma unroll
        for (int r = 0; r < 4; ++r)
          outp[(size_t)r*(NT*NP) + (t - 1)*NP] = po[r];
      }
    }
#pragma unroll
    for (int j = 0; j < 8; ++j) ax[j] = (__bf16)xv[j];
    xp += NP;
    BAR();
  }

  if (w == 0) {
    bf16x8 ahf[4];
#pragma unroll
    for (int kc = 0; kc < 4; ++kc)
      ahf[kc] = *(const bf16x8*)&hfrag[NT & 1][kc][quad][l16 & 3][0];
    float4_t p0 = {bo, bo, bo, bo};
    float4_t p1 = {0.f, 0.f, 0.f, 0.f};
    p0 = mfma_bf16(ahf[0], wof[0], p0);
    p1 = mfma_bf16(ahf[2], wof[2], p1);
    p0 = mfma_bf16(ahf[1], wof[1], p0);
    p1 = mfma_bf16(ahf[3], wof[3], p1);
    float4_t po = p0 + p1;
    if (lane == 0) {
#pragma unroll
      for (int r = 0; r < 4; ++r)
        outp[(size_t)r*(NT*NP) + (NT - 1)*NP] = po[r];
    }
  }
}

extern "C" void kernel_launch(void* const* d_in, const int* in_sizes, int n_in,
                              void* d_out, int out_size, void* d_ws, size_t ws_size,
                              hipStream_t stream) {
  const float* X    = (const float*)d_in[0];
  const float* Wih  = (const float*)d_in[1];
  const float* Whh  = (const float*)d_in[2];
  const float* bih  = (const float*)d_in[3];
  const float* bhh  = (const float*)d_in[4];
  const float* Wout = (const float*)d_in[5];
  const float* bout = (const float*)d_in[6];
  float* out = (float*)d_out;
  (void)in_sizes; (void)n_in; (void)out_size;

  // ws layout: [0, 512KB) X as bf16.
  const size_t need = (size_t)NB*NT*NP*2;
  if (d_ws != nullptr && ws_size >= need) {
    __bf16* wsX = (__bf16*)d_ws;
    xcvt<<<128, 512, 0, stream>>>(X, wsX);
    // 256 blocks = 32 nets (XCD-swizzled) x 8 batch-groups (M=4);
    // 1 block/CU; 256-reg budget via waves_per_eu(2,2).
    clstm_fused7<<<256, 512, 0, stream>>>(wsX, Wih, Whh, bih, bhh, Wout,
                                          bout, out);
  } else {
    // R8 fallback: no workspace required.
    clstm_fused_fb<<<256, 512, 0, stream>>>(X, Wih, Whh, bih, bhh, Wout,
                                            bout, out);
  }
}